// Round 3
// baseline (525.195 us; speedup 1.0000x reference)
//
#include <hip/hip_runtime.h>

// Problem constants (B=2, S=2048, HID=2048, H=16, D=128)
#define S_LEN   2048
#define HEADS   16
#define HID_DIM 2048
#define HEAD_D  128
#define BATCH   2

typedef __bf16          bf16x8 __attribute__((ext_vector_type(8)));
typedef unsigned short  u16x8  __attribute__((ext_vector_type(8)));
typedef unsigned short  u16x4  __attribute__((ext_vector_type(4)));
typedef float           f32x4  __attribute__((ext_vector_type(4)));

__device__ __forceinline__ unsigned short f2bf(float f) {
  unsigned u = __builtin_bit_cast(unsigned, f);
  u += 0x7FFFu + ((u >> 16) & 1u);          // round-to-nearest-even
  return (unsigned short)(u >> 16);
}
__device__ __forceinline__ float bf2f(unsigned short s) {
  unsigned u = ((unsigned)s) << 16;
  return __builtin_bit_cast(float, u);
}

__device__ __forceinline__ f32x4 mfma16(u16x8 a, u16x8 b, f32x4 c) {
  return __builtin_amdgcn_mfma_f32_16x16x32_bf16(
      __builtin_bit_cast(bf16x8, a), __builtin_bit_cast(bf16x8, b), c, 0, 0, 0);
}

__device__ __forceinline__ void async_load16(const void* g, void* l) {
  __builtin_amdgcn_global_load_lds(
      (const __attribute__((address_space(1))) void*)g,
      (__attribute__((address_space(3))) void*)l, 16, 0, 0);
}

// ---------------- f32 -> bf16 convert (vectorized) ----------------
__global__ __launch_bounds__(256) void cvt_bf16(const float* __restrict__ in,
                                                unsigned short* __restrict__ out,
                                                int n8) {
  for (int i = blockIdx.x * blockDim.x + threadIdx.x; i < n8;
       i += gridDim.x * blockDim.x) {
    const float4* p = (const float4*)in + 2L * i;
    float4 a = p[0], b = p[1];
    u16x8 v;
    v[0] = f2bf(a.x); v[1] = f2bf(a.y); v[2] = f2bf(a.z); v[3] = f2bf(a.w);
    v[4] = f2bf(b.x); v[5] = f2bf(b.y); v[6] = f2bf(b.z); v[7] = f2bf(b.w);
    ((u16x8*)out)[i] = v;
  }
}

// ------------- W (K x N f32) -> Wt (N x K bf16) transpose ----------
__global__ __launch_bounds__(256) void transpose_cvt(const float* __restrict__ W,
                                                     unsigned short* __restrict__ Wt,
                                                     int dim) {
  __shared__ float tile[32][33];
  const int bx = blockIdx.x * 32, by = blockIdx.y * 32;
  const int tx = threadIdx.x, ty = threadIdx.y;   // 32 x 8
#pragma unroll
  for (int i = 0; i < 32; i += 8)
    tile[ty + i][tx] = W[(long)(by + ty + i) * dim + bx + tx];
  __syncthreads();
#pragma unroll
  for (int i = 0; i < 32; i += 8)
    Wt[(long)(bx + ty + i) * dim + by + tx] = f2bf(tile[tx][ty + i]);
}

// ---- V (B*S x HID bf16) -> Vt (bh x D x S bf16) head-transpose ----
__global__ __launch_bounds__(256) void transpose_v(const unsigned short* __restrict__ V,
                                                   unsigned short* __restrict__ Vt) {
  __shared__ unsigned short tile[32][34];
  const int s0 = blockIdx.x * 32, d0 = blockIdx.y * 32, bh = blockIdx.z;
  const int b = bh >> 4, h = bh & 15;
  const int tx = threadIdx.x, ty = threadIdx.y;   // 32 x 8
#pragma unroll
  for (int i = 0; i < 32; i += 8)
    tile[ty + i][tx] =
        V[(long)(b * S_LEN + s0 + ty + i) * HID_DIM + h * HEAD_D + d0 + tx];
  __syncthreads();
#pragma unroll
  for (int i = 0; i < 32; i += 8)
    Vt[((long)bh * HEAD_D + d0 + ty + i) * S_LEN + s0 + tx] = tile[tx][ty + i];
}

// ---------------- RoPE on Q and K (in-place, bf16) -----------------
__global__ __launch_bounds__(256) void rope_qk(unsigned short* __restrict__ Qb,
                                               unsigned short* __restrict__ Kb,
                                               const float* __restrict__ fcos,
                                               const float* __restrict__ fsin) {
  const long i = (long)blockIdx.x * blockDim.x + threadIdx.x; // < B*S*H*64
  const int d = (int)(i & 63);
  const int h = (int)((i >> 6) & (HEADS - 1));
  const long row = i >> 10;                 // b*S + s
  const int s = (int)(row & (S_LEN - 1));
  const long base = row * HID_DIM + h * HEAD_D + d;
  const float c0 = fcos[s * HEAD_D + d], c1 = fcos[s * HEAD_D + d + 64];
  const float s0 = fsin[s * HEAD_D + d], s1 = fsin[s * HEAD_D + d + 64];
  const float q0 = bf2f(Qb[base]), q1 = bf2f(Qb[base + 64]);
  Qb[base]      = f2bf(q0 * c0 - q1 * s0);
  Qb[base + 64] = f2bf(q1 * c1 + q0 * s1);
  const float k0 = bf2f(Kb[base]), k1 = bf2f(Kb[base + 64]);
  Kb[base]      = f2bf(k0 * c0 - k1 * s0);
  Kb[base + 64] = f2bf(k1 * c1 + k0 * s1);
}

// ---- GEMM v2: C(MxN) = A(MxK,bf16) @ Bt(NxK,bf16)^T, dbuf 2-phase ----
// 1D grid = nbz*nby*nbx blocks (nbx = N/128, nby = M/128), XCD-swizzled.
// z selects Bt/C panel (fused QKV). Cb0 null -> write f32 to Cf.
__global__ __launch_bounds__(256) void gemm_bt2(
    const unsigned short* __restrict__ A,
    const unsigned short* __restrict__ Bt0,
    unsigned short* __restrict__ Cb0,
    float* __restrict__ Cf,
    int M, int N, int K, int nbx, long zsB, long zsC) {
  __shared__ __align__(16) unsigned short Alds[2][128 * 32];
  __shared__ __align__(16) unsigned short Blds[2][128 * 32];
  const int t = threadIdx.x;
  const int lane = t & 63;
  const int w = t >> 6;
  const int wr = w >> 1, wc = w & 1;
  const int l15 = lane & 15, l4 = lane >> 4;

  // XCD-chunked bijective swizzle (gridDim.x % 8 == 0)
  const int nwg = gridDim.x;
  const int bid = blockIdx.x;
  const int sw = (bid & 7) * (nwg >> 3) + (bid >> 3);
  const int nby = M >> 7;
  const int z = sw / (nbx * nby);
  const int rem = sw - z * nbx * nby;
  const int by = rem / nbx;
  const int bx = rem - by * nbx;

  const unsigned short* Bt = Bt0 + (long)z * zsB;
  unsigned short* Cb = Cb0 ? Cb0 + (long)z * zsC : nullptr;

  f32x4 acc[4][4] = {};

  const long rowA = (long)by * 128 + (t >> 2);
  const long rowB = (long)bx * 128 + (t >> 2);
  const int kcol = (t & 3) * 8;
  const unsigned short* aSrc = A + rowA * K + kcol;
  const unsigned short* bSrc = Bt + rowB * K + kcol;
  const long skip = 64L * K;

  const int aBase = (wr * 64 + l15) * 32 + l4 * 8;
  const int bBase = (wc * 64 + l15) * 32 + l4 * 8;

#define STAGE(buf, kt) do {                                              \
    async_load16(aSrc + (kt),        (char*)(&Alds[buf][0]) + t * 16);   \
    async_load16(aSrc + (kt) + skip, (char*)(&Alds[buf][0]) + 4096 + t * 16); \
    async_load16(bSrc + (kt),        (char*)(&Blds[buf][0]) + t * 16);   \
    async_load16(bSrc + (kt) + skip, (char*)(&Blds[buf][0]) + 4096 + t * 16); \
  } while (0)

  // prologue: stage tile 0, drain, barrier
  STAGE(0, 0);
  asm volatile("s_waitcnt vmcnt(0)" ::: "memory");
  __builtin_amdgcn_s_barrier();

  int cur = 0;
  for (int kt = 0; kt < K; kt += 32) {
    if (kt + 32 < K) STAGE(cur ^ 1, kt + 32);   // async, in flight over MFMAs
    const unsigned short* Ab = &Alds[cur][0];
    const unsigned short* Bb = &Blds[cur][0];
    u16x8 af[4], bfv[4];
#pragma unroll
    for (int m = 0; m < 4; ++m) af[m] = *(const u16x8*)&Ab[aBase + m * 512];
#pragma unroll
    for (int n = 0; n < 4; ++n) bfv[n] = *(const u16x8*)&Bb[bBase + n * 512];
#pragma unroll
    for (int m = 0; m < 4; ++m)
#pragma unroll
      for (int n = 0; n < 4; ++n)
        acc[m][n] = mfma16(af[m], bfv[n], acc[m][n]);
    __builtin_amdgcn_sched_barrier(0);   // pin MFMAs before the drain
    __syncthreads();                     // vmcnt(0)+lgkmcnt(0)+s_barrier
    cur ^= 1;
  }
#undef STAGE

  const long orow = (long)by * 128 + wr * 64 + l4 * 4;
  const long ocol = (long)bx * 128 + wc * 64 + l15;
#pragma unroll
  for (int m = 0; m < 4; ++m)
#pragma unroll
    for (int n = 0; n < 4; ++n)
#pragma unroll
      for (int r = 0; r < 4; ++r) {
        const long row = orow + m * 16 + r;
        const long col = ocol + n * 16;
        if (Cb) Cb[row * N + col] = f2bf(acc[m][n][r]);
        else    Cf[row * N + col] = acc[m][n][r];
      }
}

// --------------- fused causal+alibi flash attention v3 -------------
// 16 q-rows per wave (4096 waves -> ~50% occupancy), 64-key tiles,
// swapped QK^T (in-lane softmax), V pre-transposed (B-frags from L2),
// XCD-chunked (b,h) mapping for L2-resident K/V.
// grid: 1024 x 256.
__global__ __launch_bounds__(256) void attn_fwd3(const unsigned short* __restrict__ Q,
                                                 const unsigned short* __restrict__ K,
                                                 const unsigned short* __restrict__ Vt,
                                                 const float* __restrict__ alibi,
                                                 unsigned short* __restrict__ O) {
  __shared__ __align__(16) unsigned short Pl[4][16][72];  // per-wave P tile
  const int t = threadIdx.x;
  const int lane = t & 63;
  const int w = t >> 6;
  const int l15 = lane & 15, l4 = lane >> 4;
  // XCD-chunked swizzle: each XCD gets 4 consecutive (b,h) -> 4MB K/V in L2
  const int bid = blockIdx.x;
  const int wid = (bid & 7) * 128 + (bid >> 3);   // 1024 blocks
  const int bh = wid >> 5;             // 0..31 : (b,h)
  const int j = wid & 31;              // 0..31 : q-pair index
  const int h = bh & (HEADS - 1), b = bh >> 4;
  // causal load balance: waves get {2j, 2j+1, 126-2j, 127-2j}
  const int qt = (w < 2) ? (2 * j + w) : ((w == 2) ? (126 - 2 * j) : (127 - 2 * j));
  const int q0 = qt * 16;
  const float nslope = alibi[h * S_LEN + 1];   // = -slope_h
  const float scale = 0.08838834764831845f;    // 1/sqrt(128)

  const long rowbase = ((long)b * S_LEN) * HID_DIM + h * HEAD_D; // Q,K,O
  const long vtbase  = ((long)bh * HEAD_D) * S_LEN;              // Vt

  // Q fragments (MFMA B operand): row=q at l15, d contiguous
  u16x8 qf[4];
  {
    const unsigned short* qp = Q + rowbase + (long)(q0 + l15) * HID_DIM + l4 * 8;
#pragma unroll
    for (int ds = 0; ds < 4; ++ds) qf[ds] = *(const u16x8*)(qp + ds * 32);
  }

  f32x4 acc[8] = {};
  float m_r = -1e30f, l_r = 0.f;

  const unsigned short* kp0 = K + rowbase + (long)l15 * HID_DIM + l4 * 8;
  const unsigned short* vp0 = Vt + vtbase + (long)l15 * S_LEN + l4 * 8;

  const int nkt = (q0 >> 6) + 1;
  for (int kt = 0; kt < nkt; ++kt) {
    const int kb = kt * 64;
    // ---- QK^T swapped: S^T[k][q] (4 k-frags) ----
    f32x4 sacc[4] = {};
#pragma unroll
    for (int ds = 0; ds < 4; ++ds) {
      u16x8 kfr[4];
#pragma unroll
      for (int n = 0; n < 4; ++n)
        kfr[n] = *(const u16x8*)(kp0 + (long)(kb + 16 * n) * HID_DIM + ds * 32);
#pragma unroll
      for (int n = 0; n < 4; ++n) sacc[n] = mfma16(kfr[n], qf[ds], sacc[n]);
    }
    // ---- online softmax, in-lane over k (lane's q-col = l15) ----
    const int q = q0 + l15;
    float pv[4][4];
    float rmax = -1e30f;
#pragma unroll
    for (int n = 0; n < 4; ++n)
#pragma unroll
      for (int r = 0; r < 4; ++r) {
        const int k = kb + 16 * n + l4 * 4 + r;
        float v = sacc[n][r] * scale + nslope * (float)k;
        if (k > q) v = -1e30f;
        pv[n][r] = v;
        rmax = fmaxf(rmax, v);
      }
    rmax = fmaxf(rmax, __shfl_xor(rmax, 16, 64));
    rmax = fmaxf(rmax, __shfl_xor(rmax, 32, 64));
    const float mnew = fmaxf(m_r, rmax);
    const float sf = __expf(m_r - mnew);
    m_r = mnew;
    float rsum = 0.f;
#pragma unroll
    for (int n = 0; n < 4; ++n)
#pragma unroll
      for (int r = 0; r < 4; ++r) {
        pv[n][r] = __expf(pv[n][r] - mnew);
        rsum += pv[n][r];
      }
    rsum += __shfl_xor(rsum, 16, 64);
    rsum += __shfl_xor(rsum, 32, 64);
    l_r = l_r * sf + rsum;
    // redistribute sf (per l15=q) to O C-layout rows (q = l4*4+r)
    float sfo[4];
#pragma unroll
    for (int r = 0; r < 4; ++r) sfo[r] = __shfl(sf, l4 * 4 + r, 64);
#pragma unroll
    for (int dt = 0; dt < 8; ++dt)
#pragma unroll
      for (int r = 0; r < 4; ++r) acc[dt][r] *= sfo[r];
    // store P^T slices (4 consecutive k each) -> b64 writes
#pragma unroll
    for (int n = 0; n < 4; ++n) {
      u16x4 pk;
#pragma unroll
      for (int r = 0; r < 4; ++r) pk[r] = f2bf(pv[n][r]);
      *(u16x4*)&Pl[w][l15][16 * n + l4 * 4] = pk;
    }
    // ---- PV: A = P from LDS (b128), B = Vt straight from global ----
    u16x8 pf[2];
#pragma unroll
    for (int kf = 0; kf < 2; ++kf)
      pf[kf] = *(const u16x8*)&Pl[w][l15][kf * 32 + l4 * 8];
#pragma unroll
    for (int kf = 0; kf < 2; ++kf)
#pragma unroll
      for (int dt = 0; dt < 8; ++dt) {
        u16x8 vb = *(const u16x8*)(vp0 + (long)dt * 16 * S_LEN + kb + kf * 32);
        acc[dt] = mfma16(pf[kf], vb, acc[dt]);
      }
  }
  // ---- epilogue: normalize, store bf16 (B*S, HID) ----
  float linv[4];
#pragma unroll
  for (int r = 0; r < 4; ++r) linv[r] = 1.0f / __shfl(l_r, l4 * 4 + r, 64);
#pragma unroll
  for (int dt = 0; dt < 8; ++dt)
#pragma unroll
    for (int r = 0; r < 4; ++r) {
      const long row = q0 + l4 * 4 + r;
      O[rowbase + row * HID_DIM + dt * 16 + l15] = f2bf(acc[dt][r] * linv[r]);
    }
}

extern "C" void kernel_launch(void* const* d_in, const int* in_sizes, int n_in,
                              void* d_out, int out_size, void* d_ws, size_t ws_size,
                              hipStream_t stream) {
  const float* x    = (const float*)d_in[0];
  const float* Wq   = (const float*)d_in[1];
  const float* Wk   = (const float*)d_in[2];
  const float* Wv   = (const float*)d_in[3];
  const float* Wo   = (const float*)d_in[4];
  // d_in[5] = attention_mask (causal, reproduced analytically)
  const float* alibi = (const float*)d_in[6];
  const float* fcos  = (const float*)d_in[7];
  const float* fsin  = (const float*)d_in[8];

  char* ws = (char*)d_ws;
  // layout (bytes): xb/AO 0..16M | wtq 16..24M | wtk 24..32M | wtv 32..40M
  //                 Q 40..56M | K 56..72M | V 72..88M      (needs 88 MiB)
  // After QKV gemms: Vt reuses 24..40M, Wo^T reuses 16..24M.
  unsigned short* xb  = (unsigned short*)(ws);
  unsigned short* wtq = (unsigned short*)(ws + (16L << 20));
  unsigned short* wtk = (unsigned short*)(ws + (24L << 20));
  unsigned short* wtv = (unsigned short*)(ws + (32L << 20));
  unsigned short* VtG = (unsigned short*)(ws + (24L << 20));
  unsigned short* Qb  = (unsigned short*)(ws + (40L << 20));
  unsigned short* Kb  = (unsigned short*)(ws + (56L << 20));
  unsigned short* Vb  = (unsigned short*)(ws + (72L << 20));

  const int M = BATCH * S_LEN;   // 4096
  const int N = HID_DIM;         // 2048
  const int K = HID_DIM;         // 2048

  cvt_bf16<<<2048, 256, 0, stream>>>(x, xb, M * K / 8);

  dim3 tb(32, 8), tg(N / 32, K / 32);
  transpose_cvt<<<tg, tb, 0, stream>>>(Wq, wtq, N);
  transpose_cvt<<<tg, tb, 0, stream>>>(Wk, wtk, N);
  transpose_cvt<<<tg, tb, 0, stream>>>(Wv, wtv, N);

  // fused QKV: one dispatch, z in {0,1,2} routes Bt/C panels
  gemm_bt2<<<3 * (M / 128) * (N / 128), 256, 0, stream>>>(
      xb, wtq, Qb, nullptr, M, N, K, N / 128,
      (long)HID_DIM * HID_DIM, (long)(8 << 20));

  rope_qk<<<(BATCH * S_LEN * HEADS * 64) / 256, 256, 0, stream>>>(Qb, Kb, fcos, fsin);

  // head-transpose V -> Vt[bh][d][s]   (overwrites wtk/wtv, dead now)
  transpose_v<<<dim3(S_LEN / 32, HEAD_D / 32, BATCH * HEADS), tb, 0, stream>>>(Vb, VtG);

  transpose_cvt<<<tg, tb, 0, stream>>>(Wo, wtq, N);  // reuse wtq slot

  attn_fwd3<<<1024, 256, 0, stream>>>(Qb, Kb, VtG, alibi, xb);

  gemm_bt2<<<(M / 128) * (N / 128), 256, 0, stream>>>(
      xb, wtq, nullptr, (float*)d_out, M, N, K, N / 128, 0L, 0L);
}

// Round 4
// 324.433 us; speedup vs baseline: 1.6188x; 1.6188x over previous
//
#include <hip/hip_runtime.h>

// Problem constants (B=2, S=2048, HID=2048, H=16, D=128)
#define S_LEN   2048
#define HEADS   16
#define HID_DIM 2048
#define HEAD_D  128
#define BATCH   2

typedef __bf16          bf16x8 __attribute__((ext_vector_type(8)));
typedef unsigned short  u16x8  __attribute__((ext_vector_type(8)));
typedef unsigned short  u16x4  __attribute__((ext_vector_type(4)));
typedef float           f32x4  __attribute__((ext_vector_type(4)));

__device__ __forceinline__ unsigned short f2bf(float f) {
  unsigned u = __builtin_bit_cast(unsigned, f);
  u += 0x7FFFu + ((u >> 16) & 1u);          // round-to-nearest-even
  return (unsigned short)(u >> 16);
}
__device__ __forceinline__ float bf2f(unsigned short s) {
  unsigned u = ((unsigned)s) << 16;
  return __builtin_bit_cast(float, u);
}

__device__ __forceinline__ f32x4 mfma16(u16x8 a, u16x8 b, f32x4 c) {
  return __builtin_amdgcn_mfma_f32_16x16x32_bf16(
      __builtin_bit_cast(bf16x8, a), __builtin_bit_cast(bf16x8, b), c, 0, 0, 0);
}

__device__ __forceinline__ void async_load16(const void* g, void* l) {
  __builtin_amdgcn_global_load_lds(
      (const __attribute__((address_space(1))) void*)g,
      (__attribute__((address_space(3))) void*)l, 16, 0, 0);
}

// ---------------- f32 -> bf16 convert (vectorized) ----------------
__global__ __launch_bounds__(256) void cvt_bf16(const float* __restrict__ in,
                                                unsigned short* __restrict__ out,
                                                int n8) {
  for (int i = blockIdx.x * blockDim.x + threadIdx.x; i < n8;
       i += gridDim.x * blockDim.x) {
    const float4* p = (const float4*)in + 2L * i;
    float4 a = p[0], b = p[1];
    u16x8 v;
    v[0] = f2bf(a.x); v[1] = f2bf(a.y); v[2] = f2bf(a.z); v[3] = f2bf(a.w);
    v[4] = f2bf(b.x); v[5] = f2bf(b.y); v[6] = f2bf(b.z); v[7] = f2bf(b.w);
    ((u16x8*)out)[i] = v;
  }
}

// ------------- W (K x N f32) -> Wt (N x K bf16) transpose ----------
__global__ __launch_bounds__(256) void transpose_cvt(const float* __restrict__ W,
                                                     unsigned short* __restrict__ Wt,
                                                     int dim) {
  __shared__ float tile[32][33];
  const int bx = blockIdx.x * 32, by = blockIdx.y * 32;
  const int tx = threadIdx.x, ty = threadIdx.y;   // 32 x 8
#pragma unroll
  for (int i = 0; i < 32; i += 8)
    tile[ty + i][tx] = W[(long)(by + ty + i) * dim + bx + tx];
  __syncthreads();
#pragma unroll
  for (int i = 0; i < 32; i += 8)
    Wt[(long)(bx + ty + i) * dim + by + tx] = f2bf(tile[tx][ty + i]);
}

// ---- V (B*S x HID bf16) -> Vt (bh x D x S bf16) head-transpose ----
__global__ __launch_bounds__(256) void transpose_v(const unsigned short* __restrict__ V,
                                                   unsigned short* __restrict__ Vt) {
  __shared__ unsigned short tile[32][34];
  const int s0 = blockIdx.x * 32, d0 = blockIdx.y * 32, bh = blockIdx.z;
  const int b = bh >> 4, h = bh & 15;
  const int tx = threadIdx.x, ty = threadIdx.y;   // 32 x 8
#pragma unroll
  for (int i = 0; i < 32; i += 8)
    tile[ty + i][tx] =
        V[(long)(b * S_LEN + s0 + ty + i) * HID_DIM + h * HEAD_D + d0 + tx];
  __syncthreads();
#pragma unroll
  for (int i = 0; i < 32; i += 8)
    Vt[((long)bh * HEAD_D + d0 + ty + i) * S_LEN + s0 + tx] = tile[tx][ty + i];
}

// ---------------- RoPE on Q and K (in-place, bf16) -----------------
__global__ __launch_bounds__(256) void rope_qk(unsigned short* __restrict__ Qb,
                                               unsigned short* __restrict__ Kb,
                                               const float* __restrict__ fcos,
                                               const float* __restrict__ fsin) {
  const long i = (long)blockIdx.x * blockDim.x + threadIdx.x; // < B*S*H*64
  const int d = (int)(i & 63);
  const int h = (int)((i >> 6) & (HEADS - 1));
  const long row = i >> 10;                 // b*S + s
  const int s = (int)(row & (S_LEN - 1));
  const long base = row * HID_DIM + h * HEAD_D + d;
  const float c0 = fcos[s * HEAD_D + d], c1 = fcos[s * HEAD_D + d + 64];
  const float s0 = fsin[s * HEAD_D + d], s1 = fsin[s * HEAD_D + d + 64];
  const float q0 = bf2f(Qb[base]), q1 = bf2f(Qb[base + 64]);
  Qb[base]      = f2bf(q0 * c0 - q1 * s0);
  Qb[base + 64] = f2bf(q1 * c1 + q0 * s1);
  const float k0 = bf2f(Kb[base]), k1 = bf2f(Kb[base + 64]);
  Kb[base]      = f2bf(k0 * c0 - k1 * s0);
  Kb[base + 64] = f2bf(k1 * c1 + k0 * s1);
}

// ---- GEMM v2: C(MxN) = A(MxK,bf16) @ Bt(NxK,bf16)^T, dbuf 2-phase ----
__global__ __launch_bounds__(256) void gemm_bt2(
    const unsigned short* __restrict__ A,
    const unsigned short* __restrict__ Bt0,
    unsigned short* __restrict__ Cb0,
    float* __restrict__ Cf,
    int M, int N, int K, int nbx, long zsB, long zsC) {
  __shared__ __align__(16) unsigned short Alds[2][128 * 32];
  __shared__ __align__(16) unsigned short Blds[2][128 * 32];
  const int t = threadIdx.x;
  const int lane = t & 63;
  const int w = t >> 6;
  const int wr = w >> 1, wc = w & 1;
  const int l15 = lane & 15, l4 = lane >> 4;

  const int nwg = gridDim.x;
  const int bid = blockIdx.x;
  const int sw = (bid & 7) * (nwg >> 3) + (bid >> 3);
  const int nby = M >> 7;
  const int z = sw / (nbx * nby);
  const int rem = sw - z * nbx * nby;
  const int by = rem / nbx;
  const int bx = rem - by * nbx;

  const unsigned short* Bt = Bt0 + (long)z * zsB;
  unsigned short* Cb = Cb0 ? Cb0 + (long)z * zsC : nullptr;

  f32x4 acc[4][4] = {};

  const long rowA = (long)by * 128 + (t >> 2);
  const long rowB = (long)bx * 128 + (t >> 2);
  const int kcol = (t & 3) * 8;
  const unsigned short* aSrc = A + rowA * K + kcol;
  const unsigned short* bSrc = Bt + rowB * K + kcol;
  const long skip = 64L * K;

  const int aBase = (wr * 64 + l15) * 32 + l4 * 8;
  const int bBase = (wc * 64 + l15) * 32 + l4 * 8;

#define STAGE(buf, kt) do {                                              \
    async_load16(aSrc + (kt),        (char*)(&Alds[buf][0]) + t * 16);   \
    async_load16(aSrc + (kt) + skip, (char*)(&Alds[buf][0]) + 4096 + t * 16); \
    async_load16(bSrc + (kt),        (char*)(&Blds[buf][0]) + t * 16);   \
    async_load16(bSrc + (kt) + skip, (char*)(&Blds[buf][0]) + 4096 + t * 16); \
  } while (0)

  STAGE(0, 0);
  asm volatile("s_waitcnt vmcnt(0)" ::: "memory");
  __builtin_amdgcn_s_barrier();

  int cur = 0;
  for (int kt = 0; kt < K; kt += 32) {
    if (kt + 32 < K) STAGE(cur ^ 1, kt + 32);
    const unsigned short* Ab = &Alds[cur][0];
    const unsigned short* Bb = &Blds[cur][0];
    u16x8 af[4], bfv[4];
#pragma unroll
    for (int m = 0; m < 4; ++m) af[m] = *(const u16x8*)&Ab[aBase + m * 512];
#pragma unroll
    for (int n = 0; n < 4; ++n) bfv[n] = *(const u16x8*)&Bb[bBase + n * 512];
#pragma unroll
    for (int m = 0; m < 4; ++m)
#pragma unroll
      for (int n = 0; n < 4; ++n)
        acc[m][n] = mfma16(af[m], bfv[n], acc[m][n]);
    __builtin_amdgcn_sched_barrier(0);
    __syncthreads();
    cur ^= 1;
  }
#undef STAGE

  const long orow = (long)by * 128 + wr * 64 + l4 * 4;
  const long ocol = (long)bx * 128 + wc * 64 + l15;
#pragma unroll
  for (int m = 0; m < 4; ++m)
#pragma unroll
    for (int n = 0; n < 4; ++n)
#pragma unroll
      for (int r = 0; r < 4; ++r) {
        const long row = orow + m * 16 + r;
        const long col = ocol + n * 16;
        if (Cb) Cb[row * N + col] = f2bf(acc[m][n][r]);
        else    Cf[row * N + col] = acc[m][n][r];
      }
}

// --------------- fused causal+alibi flash attention v4 -------------
// Block-cooperative: 4 waves x 32 q-rows = 128 q-rows/block.
// K & V tiles (KVBLK=32) double-buffered in LDS via global_load_lds with
// XOR-swizzled layouts (pre-swizzled global source, swizzled reads ->
// conflict-free). Swapped QK^T, in-lane softmax, per-wave P roundtrip.
// grid: 512 blocks x 256 thr; blocks paired (qt, 15-qt) for balance.
__global__ __launch_bounds__(256) void attn_fwd4(const unsigned short* __restrict__ Q,
                                                 const unsigned short* __restrict__ K,
                                                 const unsigned short* __restrict__ Vt,
                                                 const float* __restrict__ alibi,
                                                 unsigned short* __restrict__ O) {
  __shared__ __align__(16) unsigned short Kl[2][32 * 128];  // [k][d] swz
  __shared__ __align__(16) unsigned short Vl[2][64 * 64];   // [d>>1][(d&1),k] swz
  __shared__ __align__(16) unsigned short Pl[4][32][40];    // per-wave P
  const int t = threadIdx.x;
  const int lane = t & 63;
  const int w = t >> 6;
  const int l15 = lane & 15, l4 = lane >> 4;

  // block -> (bh, qt); halves pair qt with 15-qt on the same CU
  const int bid = blockIdx.x;
  const int half = bid >> 8, r0 = bid & 255;
  const int bh = r0 & 31;
  const int qt = half ? (15 - (r0 >> 5)) : (r0 >> 5);
  const int b = bh >> 4, h = bh & 15;
  const int q0b = qt * 128;
  const int q0 = q0b + w * 32;                 // wave's first q row
  const float nslope = alibi[h * S_LEN + 1];   // = -slope_h
  const float scale = 0.08838834764831845f;    // 1/sqrt(128)

  const long rowbase = ((long)b * S_LEN) * HID_DIM + h * HEAD_D; // Q,K,O
  const long vtbase  = ((long)bh * HEAD_D) * S_LEN;              // Vt

  // Q fragments (MFMA B operand): col=q at l15, k-dim=d contiguous
  u16x8 qf[2][4];
  {
    const unsigned short* qp = Q + rowbase + (long)(q0 + l15) * HID_DIM + l4 * 8;
#pragma unroll
    for (int m = 0; m < 2; ++m)
#pragma unroll
      for (int ds = 0; ds < 4; ++ds)
        qf[m][ds] = *(const u16x8*)(qp + (long)m * 16 * HID_DIM + ds * 32);
  }

  f32x4 acc[2][8] = {};
  float m_r[2] = {-1e30f, -1e30f};
  float l_r[2] = {0.f, 0.f};

  // --- staging sources (pre-swizzled so linear LDS dest = swizzled tile) ---
  // K tile: LDS byte dd holds K[kb + dd>>8][((dd&255)^(((dd>>8)&7)<<4))/2]
  int dd, rw, cbl;
  dd = 16 * t;        rw = dd >> 8; cbl = (dd & 255) ^ ((rw & 7) << 4);
  const unsigned short* ksrc0 = K + rowbase + (long)rw * HID_DIM + (cbl >> 1);
  dd = 4096 + 16 * t; rw = dd >> 8; cbl = (dd & 255) ^ ((rw & 7) << 4);
  const unsigned short* ksrc1 = K + rowbase + (long)rw * HID_DIM + (cbl >> 1);
  // V tile rows=128B: dd -> row=dd>>7, cb_lin=(dd&127)^(((dd>>7)&3)<<4),
  //   d = 2*row + (cb_lin>>6), k = (cb_lin&63)>>1
  dd = 16 * t;        rw = dd >> 7; cbl = (dd & 127) ^ ((rw & 3) << 4);
  const unsigned short* vsrc0 =
      Vt + vtbase + (long)(2 * rw + (cbl >> 6)) * S_LEN + ((cbl & 63) >> 1);
  dd = 4096 + 16 * t; rw = dd >> 7; cbl = (dd & 127) ^ ((rw & 3) << 4);
  const unsigned short* vsrc1 =
      Vt + vtbase + (long)(2 * rw + (cbl >> 6)) * S_LEN + ((cbl & 63) >> 1);

#define ASTAGE(buf, kt_) do {                                             \
    const long kadd = (long)(kt_) * 32 * HID_DIM;                         \
    async_load16(ksrc0 + kadd, (char*)(&Kl[buf][0]) + 16 * t);            \
    async_load16(ksrc1 + kadd, (char*)(&Kl[buf][0]) + 4096 + 16 * t);     \
    async_load16(vsrc0 + (kt_) * 32, (char*)(&Vl[buf][0]) + 16 * t);      \
    async_load16(vsrc1 + (kt_) * 32, (char*)(&Vl[buf][0]) + 4096 + 16 * t); \
  } while (0)

  const int ntB = qt * 4 + 4;            // block tile count
  const int mykt = q0 >> 5;              // wave's causal last tile

  ASTAGE(0, 0);
  __syncthreads();                       // drain vmcnt, tile 0 ready

  int cur = 0;
  for (int kt = 0; kt < ntB; ++kt) {
    const int kb = kt * 32;
    if (kt + 1 < ntB) ASTAGE(cur ^ 1, kt + 1);   // prefetch next tile
    if (kt <= mykt) {
      const char* Kc = (const char*)&Kl[cur][0];
      const char* Vc = (const char*)&Vl[cur][0];
      // ---- QK^T swapped: S^T tiles [k][q] ----
      f32x4 sacc[2][2] = {};               // [n][m]
#pragma unroll
      for (int ds = 0; ds < 4; ++ds) {
        u16x8 kfr[2];
#pragma unroll
        for (int n = 0; n < 2; ++n) {
          const int R = 16 * n + l15;
          const int cb = (ds * 64 + l4 * 16) ^ ((l15 & 7) << 4);
          kfr[n] = *(const u16x8*)(Kc + R * 256 + cb);
        }
#pragma unroll
        for (int n = 0; n < 2; ++n)
#pragma unroll
          for (int m = 0; m < 2; ++m)
            sacc[n][m] = mfma16(kfr[n], qf[m][ds], sacc[n][m]);
      }
      // ---- online softmax (in-lane over k; lane's q-col = l15) ----
#pragma unroll
      for (int m = 0; m < 2; ++m) {
        const int q = q0 + 16 * m + l15;
        float pv[2][4];
        float rmax = -1e30f;
#pragma unroll
        for (int n = 0; n < 2; ++n)
#pragma unroll
          for (int r = 0; r < 4; ++r) {
            const int k = kb + 16 * n + l4 * 4 + r;
            float v = sacc[n][m][r] * scale + nslope * (float)k;
            if (k > q) v = -1e30f;
            pv[n][r] = v;
            rmax = fmaxf(rmax, v);
          }
        rmax = fmaxf(rmax, __shfl_xor(rmax, 16, 64));
        rmax = fmaxf(rmax, __shfl_xor(rmax, 32, 64));
        const float mnew = fmaxf(m_r[m], rmax);
        const float sf = __expf(m_r[m] - mnew);
        m_r[m] = mnew;
        float rsum = 0.f;
#pragma unroll
        for (int n = 0; n < 2; ++n)
#pragma unroll
          for (int r = 0; r < 4; ++r) {
            pv[n][r] = __expf(pv[n][r] - mnew);
            rsum += pv[n][r];
          }
        rsum += __shfl_xor(rsum, 16, 64);
        rsum += __shfl_xor(rsum, 32, 64);
        l_r[m] = l_r[m] * sf + rsum;
        float sfo[4];
#pragma unroll
        for (int r = 0; r < 4; ++r) sfo[r] = __shfl(sf, l4 * 4 + r, 64);
#pragma unroll
        for (int dt = 0; dt < 8; ++dt)
#pragma unroll
          for (int r = 0; r < 4; ++r) acc[m][dt][r] *= sfo[r];
#pragma unroll
        for (int n = 0; n < 2; ++n) {
          u16x4 pk;
#pragma unroll
          for (int r = 0; r < 4; ++r) pk[r] = f2bf(pv[n][r]);
          *(u16x4*)&Pl[w][16 * m + l15][16 * n + l4 * 4] = pk;
        }
      }
      // ---- PV: A = P (LDS, per-wave), B = V tile (LDS, swizzled) ----
      u16x8 pf[2];
#pragma unroll
      for (int m = 0; m < 2; ++m)
        pf[m] = *(const u16x8*)&Pl[w][16 * m + l15][l4 * 8];
#pragma unroll
      for (int dt = 0; dt < 8; ++dt) {
        const int d = dt * 16 + l15;
        const int vrow = d >> 1;
        const int cbv = (((d & 1) << 6) | (l4 << 4)) ^ ((vrow & 3) << 4);
        u16x8 vb = *(const u16x8*)(Vc + vrow * 128 + cbv);
#pragma unroll
        for (int m = 0; m < 2; ++m)
          acc[m][dt] = mfma16(pf[m], vb, acc[m][dt]);
      }
    }
    __builtin_amdgcn_sched_barrier(0);
    __syncthreads();                     // buf reads done + next tile landed
    cur ^= 1;
  }
#undef ASTAGE

  // ---- epilogue: normalize, store bf16 (B*S, HID) ----
#pragma unroll
  for (int m = 0; m < 2; ++m) {
    float linv[4];
#pragma unroll
    for (int r = 0; r < 4; ++r)
      linv[r] = 1.0f / __shfl(l_r[m], l4 * 4 + r, 64);
#pragma unroll
    for (int dt = 0; dt < 8; ++dt)
#pragma unroll
      for (int r = 0; r < 4; ++r) {
        const long row = q0 + 16 * m + l4 * 4 + r;
        O[rowbase + row * HID_DIM + dt * 16 + l15] = f2bf(acc[m][dt][r] * linv[r]);
      }
  }
}

extern "C" void kernel_launch(void* const* d_in, const int* in_sizes, int n_in,
                              void* d_out, int out_size, void* d_ws, size_t ws_size,
                              hipStream_t stream) {
  const float* x    = (const float*)d_in[0];
  const float* Wq   = (const float*)d_in[1];
  const float* Wk   = (const float*)d_in[2];
  const float* Wv   = (const float*)d_in[3];
  const float* Wo   = (const float*)d_in[4];
  // d_in[5] = attention_mask (causal, reproduced analytically)
  const float* alibi = (const float*)d_in[6];
  const float* fcos  = (const float*)d_in[7];
  const float* fsin  = (const float*)d_in[8];

  char* ws = (char*)d_ws;
  unsigned short* xb  = (unsigned short*)(ws);
  unsigned short* wtq = (unsigned short*)(ws + (16L << 20));
  unsigned short* wtk = (unsigned short*)(ws + (24L << 20));
  unsigned short* wtv = (unsigned short*)(ws + (32L << 20));
  unsigned short* VtG = (unsigned short*)(ws + (24L << 20));
  unsigned short* Qb  = (unsigned short*)(ws + (40L << 20));
  unsigned short* Kb  = (unsigned short*)(ws + (56L << 20));
  unsigned short* Vb  = (unsigned short*)(ws + (72L << 20));

  const int M = BATCH * S_LEN;   // 4096
  const int N = HID_DIM;         // 2048
  const int K = HID_DIM;         // 2048

  cvt_bf16<<<2048, 256, 0, stream>>>(x, xb, M * K / 8);

  dim3 tb(32, 8), tg(N / 32, K / 32);
  transpose_cvt<<<tg, tb, 0, stream>>>(Wq, wtq, N);
  transpose_cvt<<<tg, tb, 0, stream>>>(Wk, wtk, N);
  transpose_cvt<<<tg, tb, 0, stream>>>(Wv, wtv, N);

  gemm_bt2<<<3 * (M / 128) * (N / 128), 256, 0, stream>>>(
      xb, wtq, Qb, nullptr, M, N, K, N / 128,
      (long)HID_DIM * HID_DIM, (long)(8 << 20));

  rope_qk<<<(BATCH * S_LEN * HEADS * 64) / 256, 256, 0, stream>>>(Qb, Kb, fcos, fsin);

  transpose_v<<<dim3(S_LEN / 32, HEAD_D / 32, BATCH * HEADS), tb, 0, stream>>>(Vb, VtG);

  transpose_cvt<<<tg, tb, 0, stream>>>(Wo, wtq, N);

  attn_fwd4<<<512, 256, 0, stream>>>(Qb, Kb, VtG, alibi, xb);

  gemm_bt2<<<(M / 128) * (N / 128), 256, 0, stream>>>(
      xb, wtq, nullptr, (float*)d_out, M, N, K, N / 128, 0L, 0L);
}

// Round 5
// 318.770 us; speedup vs baseline: 1.6476x; 1.0178x over previous
//
#include <hip/hip_runtime.h>

// Problem constants (B=2, S=2048, HID=2048, H=16, D=128)
#define S_LEN   2048
#define HEADS   16
#define HID_DIM 2048
#define HEAD_D  128
#define BATCH   2

typedef __bf16          bf16x8 __attribute__((ext_vector_type(8)));
typedef unsigned short  u16x8  __attribute__((ext_vector_type(8)));
typedef unsigned short  u16x4  __attribute__((ext_vector_type(4)));
typedef float           f32x4  __attribute__((ext_vector_type(4)));

__device__ __forceinline__ unsigned short f2bf(float f) {
  unsigned u = __builtin_bit_cast(unsigned, f);
  u += 0x7FFFu + ((u >> 16) & 1u);          // round-to-nearest-even
  return (unsigned short)(u >> 16);
}
__device__ __forceinline__ float bf2f(unsigned short s) {
  unsigned u = ((unsigned)s) << 16;
  return __builtin_bit_cast(float, u);
}

__device__ __forceinline__ f32x4 mfma16(u16x8 a, u16x8 b, f32x4 c) {
  return __builtin_amdgcn_mfma_f32_16x16x32_bf16(
      __builtin_bit_cast(bf16x8, a), __builtin_bit_cast(bf16x8, b), c, 0, 0, 0);
}

__device__ __forceinline__ void async_load16(const void* g, void* l) {
  __builtin_amdgcn_global_load_lds(
      (const __attribute__((address_space(1))) void*)g,
      (__attribute__((address_space(3))) void*)l, 16, 0, 0);
}

// ---------------- f32 -> bf16 convert (vectorized) ----------------
__global__ __launch_bounds__(256) void cvt_bf16(const float* __restrict__ in,
                                                unsigned short* __restrict__ out,
                                                int n8) {
  for (int i = blockIdx.x * blockDim.x + threadIdx.x; i < n8;
       i += gridDim.x * blockDim.x) {
    const float4* p = (const float4*)in + 2L * i;
    float4 a = p[0], b = p[1];
    u16x8 v;
    v[0] = f2bf(a.x); v[1] = f2bf(a.y); v[2] = f2bf(a.z); v[3] = f2bf(a.w);
    v[4] = f2bf(b.x); v[5] = f2bf(b.y); v[6] = f2bf(b.z); v[7] = f2bf(b.w);
    ((u16x8*)out)[i] = v;
  }
}

// ---- W (K x N f32) -> Wt (N x K bf16) transpose; z picks one of 3 ----
__global__ __launch_bounds__(256) void transpose_cvt3(
    const float* __restrict__ W0, const float* __restrict__ W1,
    const float* __restrict__ W2, unsigned short* __restrict__ O0,
    unsigned short* __restrict__ O1, unsigned short* __restrict__ O2,
    int dim) {
  __shared__ float tile[32][33];
  const int z = blockIdx.z;
  const float* W = (z == 0) ? W0 : (z == 1) ? W1 : W2;
  unsigned short* Wt = (z == 0) ? O0 : (z == 1) ? O1 : O2;
  const int bx = blockIdx.x * 32, by = blockIdx.y * 32;
  const int tx = threadIdx.x, ty = threadIdx.y;   // 32 x 8
#pragma unroll
  for (int i = 0; i < 32; i += 8)
    tile[ty + i][tx] = W[(long)(by + ty + i) * dim + bx + tx];
  __syncthreads();
#pragma unroll
  for (int i = 0; i < 32; i += 8)
    Wt[(long)(bx + ty + i) * dim + by + tx] = f2bf(tile[tx][ty + i]);
}

__global__ __launch_bounds__(256) void transpose_cvt(const float* __restrict__ W,
                                                     unsigned short* __restrict__ Wt,
                                                     int dim) {
  __shared__ float tile[32][33];
  const int bx = blockIdx.x * 32, by = blockIdx.y * 32;
  const int tx = threadIdx.x, ty = threadIdx.y;   // 32 x 8
#pragma unroll
  for (int i = 0; i < 32; i += 8)
    tile[ty + i][tx] = W[(long)(by + ty + i) * dim + bx + tx];
  __syncthreads();
#pragma unroll
  for (int i = 0; i < 32; i += 8)
    Wt[(long)(bx + ty + i) * dim + by + tx] = f2bf(tile[tx][ty + i]);
}

// ---- V (B*S x HID bf16) -> Vt (bh x D x S bf16) head-transpose ----
__global__ __launch_bounds__(256) void transpose_v(const unsigned short* __restrict__ V,
                                                   unsigned short* __restrict__ Vt) {
  __shared__ unsigned short tile[32][34];
  const int s0 = blockIdx.x * 32, d0 = blockIdx.y * 32, bh = blockIdx.z;
  const int b = bh >> 4, h = bh & 15;
  const int tx = threadIdx.x, ty = threadIdx.y;   // 32 x 8
#pragma unroll
  for (int i = 0; i < 32; i += 8)
    tile[ty + i][tx] =
        V[(long)(b * S_LEN + s0 + ty + i) * HID_DIM + h * HEAD_D + d0 + tx];
  __syncthreads();
#pragma unroll
  for (int i = 0; i < 32; i += 8)
    Vt[((long)bh * HEAD_D + d0 + ty + i) * S_LEN + s0 + tx] = tile[tx][ty + i];
}

// ---------------- RoPE on Q and K (in-place, bf16) -----------------
__global__ __launch_bounds__(256) void rope_qk(unsigned short* __restrict__ Qb,
                                               unsigned short* __restrict__ Kb,
                                               const float* __restrict__ fcos,
                                               const float* __restrict__ fsin) {
  const long i = (long)blockIdx.x * blockDim.x + threadIdx.x; // < B*S*H*64
  const int d = (int)(i & 63);
  const int h = (int)((i >> 6) & (HEADS - 1));
  const long row = i >> 10;                 // b*S + s
  const int s = (int)(row & (S_LEN - 1));
  const long base = row * HID_DIM + h * HEAD_D + d;
  const float c0 = fcos[s * HEAD_D + d], c1 = fcos[s * HEAD_D + d + 64];
  const float s0 = fsin[s * HEAD_D + d], s1 = fsin[s * HEAD_D + d + 64];
  const float q0 = bf2f(Qb[base]), q1 = bf2f(Qb[base + 64]);
  Qb[base]      = f2bf(q0 * c0 - q1 * s0);
  Qb[base + 64] = f2bf(q1 * c1 + q0 * s1);
  const float k0 = bf2f(Kb[base]), k1 = bf2f(Kb[base + 64]);
  Kb[base]      = f2bf(k0 * c0 - k1 * s0);
  Kb[base + 64] = f2bf(k1 * c1 + k0 * s1);
}

// ---- GEMM v3: C(MxN) = A(MxK,bf16) @ Bt(NxK,bf16)^T ----
// 3-deep LDS pipeline, counted vmcnt (never 0 in steady state),
// XOR-swizzled LDS tiles (pre-swizzled global source, swizzled ds_read).
__global__ __launch_bounds__(256) void gemm_bt3(
    const unsigned short* __restrict__ A,
    const unsigned short* __restrict__ Bt0,
    unsigned short* __restrict__ Cb0,
    float* __restrict__ Cf,
    int M, int N, int K, int nbx, long zsB, long zsC) {
  __shared__ __align__(16) unsigned short Alds[3][128 * 32];
  __shared__ __align__(16) unsigned short Blds[3][128 * 32];
  const int t = threadIdx.x;
  const int lane = t & 63;
  const int w = t >> 6;
  const int wr = w >> 1, wc = w & 1;
  const int l15 = lane & 15, l4 = lane >> 4;

  // XCD-chunked bijective swizzle (gridDim.x % 8 == 0)
  const int nwg = gridDim.x;
  const int bid = blockIdx.x;
  const int sw = (bid & 7) * (nwg >> 3) + (bid >> 3);
  const int nby = M >> 7;
  const int z = sw / (nbx * nby);
  const int rem = sw - z * nbx * nby;
  const int by = rem / nbx;
  const int bx = rem - by * nbx;

  const unsigned short* Bt = Bt0 + (long)z * zsB;
  unsigned short* Cb = Cb0 ? Cb0 + (long)z * zsC : nullptr;

  f32x4 acc[4][4] = {};

  const long rowA = (long)by * 128 + (t >> 2);
  const long rowB = (long)bx * 128 + (t >> 2);
  // pre-swizzled source column: linear LDS dest + swizzled read = consistent
  const int kcol = 8 * ((t & 3) ^ ((t >> 3) & 3));
  const unsigned short* aSrc = A + rowA * K + kcol;
  const unsigned short* bSrc = Bt + rowB * K + kcol;
  const long skip = 64L * K;

  // swizzled fragment read base (conflict-free: 2 lanes per 16B slot)
  const int swz = (l4 ^ ((l15 >> 1) & 3)) * 8;
  const int aBase = (wr * 64 + l15) * 32 + swz;
  const int bBase = (wc * 64 + l15) * 32 + swz;

#define STAGE(buf, kt) do {                                              \
    async_load16(aSrc + (kt),        (char*)(&Alds[buf][0]) + t * 16);   \
    async_load16(aSrc + (kt) + skip, (char*)(&Alds[buf][0]) + 4096 + t * 16); \
    async_load16(bSrc + (kt),        (char*)(&Blds[buf][0]) + t * 16);   \
    async_load16(bSrc + (kt) + skip, (char*)(&Blds[buf][0]) + 4096 + t * 16); \
  } while (0)

  const int KT = K >> 5;
  STAGE(0, 0);
  STAGE(1, 32);

  int cur = 0;
  for (int it = 0; it < KT; ++it) {
    // wait for tile `it` (4 oldest loads); next tile's 4 stay in flight
    if (it + 1 < KT) asm volatile("s_waitcnt vmcnt(4)" ::: "memory");
    else             asm volatile("s_waitcnt vmcnt(0)" ::: "memory");
    asm volatile("s_barrier" ::: "memory");
    if (it + 2 < KT) {
      const int nb = (cur + 2 >= 3) ? cur - 1 : cur + 2;
      STAGE(nb, (it + 2) * 32);
    }
    const unsigned short* Ab = &Alds[cur][0];
    const unsigned short* Bb = &Blds[cur][0];
    u16x8 af[4], bfv[4];
#pragma unroll
    for (int m = 0; m < 4; ++m) af[m] = *(const u16x8*)&Ab[aBase + m * 512];
#pragma unroll
    for (int n = 0; n < 4; ++n) bfv[n] = *(const u16x8*)&Bb[bBase + n * 512];
#pragma unroll
    for (int m = 0; m < 4; ++m)
#pragma unroll
      for (int n = 0; n < 4; ++n)
        acc[m][n] = mfma16(af[m], bfv[n], acc[m][n]);
    cur = (cur + 1 >= 3) ? 0 : cur + 1;
  }
#undef STAGE

  const long orow = (long)by * 128 + wr * 64 + l4 * 4;
  const long ocol = (long)bx * 128 + wc * 64 + l15;
#pragma unroll
  for (int m = 0; m < 4; ++m)
#pragma unroll
    for (int n = 0; n < 4; ++n)
#pragma unroll
      for (int r = 0; r < 4; ++r) {
        const long row = orow + m * 16 + r;
        const long col = ocol + n * 16;
        if (Cb) Cb[row * N + col] = f2bf(acc[m][n][r]);
        else    Cf[row * N + col] = acc[m][n][r];
      }
}

// --------------- fused causal+alibi flash attention v5 -------------
// Same as v4 (block-cooperative, swizzled LDS K/V staging, swapped QK^T)
// but XCD-chunked: each XCD owns 4 consecutive (b,h) -> K/V set = 4MB = L2.
// qt paired (ql, 15-ql) across the idx range for per-CU causal balance.
__global__ __launch_bounds__(256) void attn_fwd5(const unsigned short* __restrict__ Q,
                                                 const unsigned short* __restrict__ K,
                                                 const unsigned short* __restrict__ Vt,
                                                 const float* __restrict__ alibi,
                                                 unsigned short* __restrict__ O) {
  __shared__ __align__(16) unsigned short Kl[2][32 * 128];  // [k][d] swz
  __shared__ __align__(16) unsigned short Vl[2][64 * 64];   // [d>>1][(d&1),k] swz
  __shared__ __align__(16) unsigned short Pl[4][32][40];    // per-wave P
  const int t = threadIdx.x;
  const int lane = t & 63;
  const int w = t >> 6;
  const int l15 = lane & 15, l4 = lane >> 4;

  // XCD-chunked mapping: xcd = bid&7 owns bh in [xcd*4, xcd*4+4)
  const int bid = blockIdx.x;                 // 512 blocks
  const int xcd = bid & 7;
  const int idx = bid >> 3;                   // 0..63
  const int qh = idx >> 4;                    // 0..3  (bh within xcd)
  const int ql = idx & 15;
  const int qt = (qh < 2) ? ql : (15 - ql);   // per-CU pairs sum to 15
  const int bh = xcd * 4 + qh;
  const int b = bh >> 4, h = bh & 15;
  const int q0b = qt * 128;
  const int q0 = q0b + w * 32;                 // wave's first q row
  const float nslope = alibi[h * S_LEN + 1];   // = -slope_h
  const float scale = 0.08838834764831845f;    // 1/sqrt(128)

  const long rowbase = ((long)b * S_LEN) * HID_DIM + h * HEAD_D; // Q,K,O
  const long vtbase  = ((long)bh * HEAD_D) * S_LEN;              // Vt

  // Q fragments (MFMA B operand): col=q at l15, k-dim=d contiguous
  u16x8 qf[2][4];
  {
    const unsigned short* qp = Q + rowbase + (long)(q0 + l15) * HID_DIM + l4 * 8;
#pragma unroll
    for (int m = 0; m < 2; ++m)
#pragma unroll
      for (int ds = 0; ds < 4; ++ds)
        qf[m][ds] = *(const u16x8*)(qp + (long)m * 16 * HID_DIM + ds * 32);
  }

  f32x4 acc[2][8] = {};
  float m_r[2] = {-1e30f, -1e30f};
  float l_r[2] = {0.f, 0.f};

  // --- staging sources (pre-swizzled so linear LDS dest = swizzled tile) ---
  int dd, rw, cbl;
  dd = 16 * t;        rw = dd >> 8; cbl = (dd & 255) ^ ((rw & 7) << 4);
  const unsigned short* ksrc0 = K + rowbase + (long)rw * HID_DIM + (cbl >> 1);
  dd = 4096 + 16 * t; rw = dd >> 8; cbl = (dd & 255) ^ ((rw & 7) << 4);
  const unsigned short* ksrc1 = K + rowbase + (long)rw * HID_DIM + (cbl >> 1);
  dd = 16 * t;        rw = dd >> 7; cbl = (dd & 127) ^ ((rw & 3) << 4);
  const unsigned short* vsrc0 =
      Vt + vtbase + (long)(2 * rw + (cbl >> 6)) * S_LEN + ((cbl & 63) >> 1);
  dd = 4096 + 16 * t; rw = dd >> 7; cbl = (dd & 127) ^ ((rw & 3) << 4);
  const unsigned short* vsrc1 =
      Vt + vtbase + (long)(2 * rw + (cbl >> 6)) * S_LEN + ((cbl & 63) >> 1);

#define ASTAGE(buf, kt_) do {                                             \
    const long kadd = (long)(kt_) * 32 * HID_DIM;                         \
    async_load16(ksrc0 + kadd, (char*)(&Kl[buf][0]) + 16 * t);            \
    async_load16(ksrc1 + kadd, (char*)(&Kl[buf][0]) + 4096 + 16 * t);     \
    async_load16(vsrc0 + (kt_) * 32, (char*)(&Vl[buf][0]) + 16 * t);      \
    async_load16(vsrc1 + (kt_) * 32, (char*)(&Vl[buf][0]) + 4096 + 16 * t); \
  } while (0)

  const int ntB = qt * 4 + 4;            // block tile count
  const int mykt = q0 >> 5;              // wave's causal last tile

  ASTAGE(0, 0);
  __syncthreads();                       // drain vmcnt, tile 0 ready

  int cur = 0;
  for (int kt = 0; kt < ntB; ++kt) {
    const int kb = kt * 32;
    if (kt + 1 < ntB) ASTAGE(cur ^ 1, kt + 1);   // prefetch next tile
    if (kt <= mykt) {
      const char* Kc = (const char*)&Kl[cur][0];
      const char* Vc = (const char*)&Vl[cur][0];
      // ---- QK^T swapped: S^T tiles [k][q] ----
      f32x4 sacc[2][2] = {};               // [n][m]
#pragma unroll
      for (int ds = 0; ds < 4; ++ds) {
        u16x8 kfr[2];
#pragma unroll
        for (int n = 0; n < 2; ++n) {
          const int R = 16 * n + l15;
          const int cb = (ds * 64 + l4 * 16) ^ ((l15 & 7) << 4);
          kfr[n] = *(const u16x8*)(Kc + R * 256 + cb);
        }
#pragma unroll
        for (int n = 0; n < 2; ++n)
#pragma unroll
          for (int m = 0; m < 2; ++m)
            sacc[n][m] = mfma16(kfr[n], qf[m][ds], sacc[n][m]);
      }
      // ---- online softmax (in-lane over k; lane's q-col = l15) ----
#pragma unroll
      for (int m = 0; m < 2; ++m) {
        const int q = q0 + 16 * m + l15;
        float pv[2][4];
        float rmax = -1e30f;
#pragma unroll
        for (int n = 0; n < 2; ++n)
#pragma unroll
          for (int r = 0; r < 4; ++r) {
            const int k = kb + 16 * n + l4 * 4 + r;
            float v = sacc[n][m][r] * scale + nslope * (float)k;
            if (k > q) v = -1e30f;
            pv[n][r] = v;
            rmax = fmaxf(rmax, v);
          }
        rmax = fmaxf(rmax, __shfl_xor(rmax, 16, 64));
        rmax = fmaxf(rmax, __shfl_xor(rmax, 32, 64));
        const float mnew = fmaxf(m_r[m], rmax);
        const float sf = __expf(m_r[m] - mnew);
        m_r[m] = mnew;
        float rsum = 0.f;
#pragma unroll
        for (int n = 0; n < 2; ++n)
#pragma unroll
          for (int r = 0; r < 4; ++r) {
            pv[n][r] = __expf(pv[n][r] - mnew);
            rsum += pv[n][r];
          }
        rsum += __shfl_xor(rsum, 16, 64);
        rsum += __shfl_xor(rsum, 32, 64);
        l_r[m] = l_r[m] * sf + rsum;
        float sfo[4];
#pragma unroll
        for (int r = 0; r < 4; ++r) sfo[r] = __shfl(sf, l4 * 4 + r, 64);
#pragma unroll
        for (int dt = 0; dt < 8; ++dt)
#pragma unroll
          for (int r = 0; r < 4; ++r) acc[m][dt][r] *= sfo[r];
#pragma unroll
        for (int n = 0; n < 2; ++n) {
          u16x4 pk;
#pragma unroll
          for (int r = 0; r < 4; ++r) pk[r] = f2bf(pv[n][r]);
          *(u16x4*)&Pl[w][16 * m + l15][16 * n + l4 * 4] = pk;
        }
      }
      // ---- PV: A = P (LDS, per-wave), B = V tile (LDS, swizzled) ----
      u16x8 pf[2];
#pragma unroll
      for (int m = 0; m < 2; ++m)
        pf[m] = *(const u16x8*)&Pl[w][16 * m + l15][l4 * 8];
#pragma unroll
      for (int dt = 0; dt < 8; ++dt) {
        const int d = dt * 16 + l15;
        const int vrow = d >> 1;
        const int cbv = (((d & 1) << 6) | (l4 << 4)) ^ ((vrow & 3) << 4);
        u16x8 vb = *(const u16x8*)(Vc + vrow * 128 + cbv);
#pragma unroll
        for (int m = 0; m < 2; ++m)
          acc[m][dt] = mfma16(pf[m], vb, acc[m][dt]);
      }
    }
    __builtin_amdgcn_sched_barrier(0);
    __syncthreads();                     // buf reads done + next tile landed
    cur ^= 1;
  }
#undef ASTAGE

  // ---- epilogue: normalize, store bf16 (B*S, HID) ----
#pragma unroll
  for (int m = 0; m < 2; ++m) {
    float linv[4];
#pragma unroll
    for (int r = 0; r < 4; ++r)
      linv[r] = 1.0f / __shfl(l_r[m], l4 * 4 + r, 64);
#pragma unroll
    for (int dt = 0; dt < 8; ++dt)
#pragma unroll
      for (int r = 0; r < 4; ++r) {
        const long row = q0 + 16 * m + l4 * 4 + r;
        O[rowbase + row * HID_DIM + dt * 16 + l15] = f2bf(acc[m][dt][r] * linv[r]);
      }
  }
}

extern "C" void kernel_launch(void* const* d_in, const int* in_sizes, int n_in,
                              void* d_out, int out_size, void* d_ws, size_t ws_size,
                              hipStream_t stream) {
  const float* x    = (const float*)d_in[0];
  const float* Wq   = (const float*)d_in[1];
  const float* Wk   = (const float*)d_in[2];
  const float* Wv   = (const float*)d_in[3];
  const float* Wo   = (const float*)d_in[4];
  // d_in[5] = attention_mask (causal, reproduced analytically)
  const float* alibi = (const float*)d_in[6];
  const float* fcos  = (const float*)d_in[7];
  const float* fsin  = (const float*)d_in[8];

  char* ws = (char*)d_ws;
  unsigned short* xb  = (unsigned short*)(ws);
  unsigned short* wtq = (unsigned short*)(ws + (16L << 20));
  unsigned short* wtk = (unsigned short*)(ws + (24L << 20));
  unsigned short* wtv = (unsigned short*)(ws + (32L << 20));
  unsigned short* VtG = (unsigned short*)(ws + (24L << 20));
  unsigned short* Qb  = (unsigned short*)(ws + (40L << 20));
  unsigned short* Kb  = (unsigned short*)(ws + (56L << 20));
  unsigned short* Vb  = (unsigned short*)(ws + (72L << 20));

  const int M = BATCH * S_LEN;   // 4096
  const int N = HID_DIM;         // 2048
  const int K = HID_DIM;         // 2048

  cvt_bf16<<<2048, 256, 0, stream>>>(x, xb, M * K / 8);

  dim3 tb(32, 8);
  transpose_cvt3<<<dim3(N / 32, K / 32, 3), tb, 0, stream>>>(
      Wq, Wk, Wv, wtq, wtk, wtv, N);

  gemm_bt3<<<3 * (M / 128) * (N / 128), 256, 0, stream>>>(
      xb, wtq, Qb, nullptr, M, N, K, N / 128,
      (long)HID_DIM * HID_DIM, (long)(8 << 20));

  rope_qk<<<(BATCH * S_LEN * HEADS * 64) / 256, 256, 0, stream>>>(Qb, Kb, fcos, fsin);

  transpose_v<<<dim3(S_LEN / 32, HEAD_D / 32, BATCH * HEADS), tb, 0, stream>>>(Vb, VtG);

  transpose_cvt<<<dim3(N / 32, K / 32), tb, 0, stream>>>(Wo, wtq, N);

  attn_fwd5<<<512, 256, 0, stream>>>(Qb, Kb, VtG, alibi, xb);

  gemm_bt3<<<(M / 128) * (N / 128), 256, 0, stream>>>(
      xb, wtq, nullptr, (float*)d_out, M, N, K, N / 128, 0L, 0L);
}